// Round 3
// baseline (579.302 us; speedup 1.0000x reference)
//
#include <hip/hip_runtime.h>

// Model: e = maxpool_L(relu(x @ Wc^T + bc)); feat = [e1-e2, e1*e2];
//        h = tanh(feat @ W1^T + b1); out = h @ W2^T + b2
// Sizes: B=2048, L=64, D=300, C=512, H=2048, O=1.
// Inputs fp32 (proven: round-2 dtype detector took F=0 -> identical output to
// round 1). Output fp32 (harness contract; rounds 1-2 failed by writing bf16
// into the float* buffer). bf16 MFMA for encode + fc1; fc2 fused into fc1's
// epilogue in fp32 registers (no h round-trip) for precision margin.

#define B_SZ 2048
#define L_SZ 64
#define D_SZ 300
#define C_SZ 512
#define H_SZ 2048
#define KPAD 320      // D padded to multiple of 32 (zeros)
#define LDSPITCH 328  // KPAD+8: break power-of-2 LDS stride aliasing

typedef __bf16 bf16x8 __attribute__((ext_vector_type(8)));
typedef float f32x4 __attribute__((ext_vector_type(4)));

__device__ __forceinline__ unsigned short f2bf(float f) {
  unsigned int u = __float_as_uint(f);
  u += 0x7fffu + ((u >> 16) & 1u);   // RNE
  return (unsigned short)(u >> 16);
}

// ---- kernel 0: Wc -> bf16 [512][320] (zero K-pad), W1 -> bf16 [2048][1024]
__global__ __launch_bounds__(256)
void convert_kernel(const float* __restrict__ Wc, const float* __restrict__ W1,
                    unsigned short* __restrict__ Wcb, unsigned short* __restrict__ W1b) {
  int id = blockIdx.x * 256 + threadIdx.x;
  if (id < C_SZ * KPAD) {
    int c = id / KPAD, k = id - c * KPAD;
    Wcb[id] = (k < D_SZ) ? f2bf(Wc[c * D_SZ + k]) : (unsigned short)0;
  } else {
    int id2 = id - C_SZ * KPAD;
    if (id2 < H_SZ * 2 * C_SZ) W1b[id2] = f2bf(W1[id2]);
  }
}

// ---- kernel 1: encode. One block per (batch, which-input). M=64, N=512, K=320.
__global__ __launch_bounds__(256, 2)
void encode_kernel(const float* __restrict__ x1, const float* __restrict__ x2,
                   const unsigned short* __restrict__ Wcb,
                   const float* __restrict__ bc, float* __restrict__ e) {
  const int b = blockIdx.x, z = blockIdx.y;
  const float* __restrict__ x = (z ? x2 : x1) + (size_t)b * (L_SZ * D_SZ);
  __shared__ unsigned short xs[L_SZ * LDSPITCH];  // 41,984 B
  const int tid = threadIdx.x;

  // stage x[b] fp32 -> bf16 LDS (75 float4 per word-row)
  const float4* __restrict__ xv = reinterpret_cast<const float4*>(x);
  for (int i = tid; i < (L_SZ * D_SZ / 4); i += 256) {
    float4 v = xv[i];
    int word = i / 75, col = (i - word * 75) * 4;
    unsigned int lo = (unsigned int)f2bf(v.x) | ((unsigned int)f2bf(v.y) << 16);
    unsigned int hi = (unsigned int)f2bf(v.z) | ((unsigned int)f2bf(v.w) << 16);
    *reinterpret_cast<uint2*>(&xs[word * LDSPITCH + col]) = make_uint2(lo, hi);
  }
  for (int i = tid; i < L_SZ * (KPAD - D_SZ); i += 256) {  // zero K-pad cols
    int word = i / 20, c = D_SZ + (i - word * 20);
    xs[word * LDSPITCH + c] = 0;
  }
  __syncthreads();

  const int wave = tid >> 6, lane = tid & 63;
  const int l16 = lane & 15, quad = lane >> 4;
  const int koff = quad * 8;

  f32x4 acc[4][8];
  #pragma unroll
  for (int mt = 0; mt < 4; ++mt)
    #pragma unroll
    for (int nt = 0; nt < 8; ++nt)
      #pragma unroll
      for (int r = 0; r < 4; ++r) acc[mt][nt][r] = 0.f;

  // wave w covers channels [w*128, w*128+128)
  #pragma unroll
  for (int ks = 0; ks < KPAD / 32; ++ks) {
    bf16x8 a[4];
    #pragma unroll
    for (int mt = 0; mt < 4; ++mt)
      a[mt] = *reinterpret_cast<const bf16x8*>(&xs[(mt * 16 + l16) * LDSPITCH + ks * 32 + koff]);
    #pragma unroll
    for (int nt = 0; nt < 8; ++nt) {
      int c = wave * 128 + nt * 16 + l16;
      bf16x8 bw = *reinterpret_cast<const bf16x8*>(Wcb + c * KPAD + ks * 32 + koff);
      #pragma unroll
      for (int mt = 0; mt < 4; ++mt)
        acc[mt][nt] = __builtin_amdgcn_mfma_f32_16x16x32_bf16(a[mt], bw, acc[mt][nt], 0, 0, 0);
    }
  }

  // +bias, relu, max over the 64 words (C/D: row=quad*4+r, col=l16)
  #pragma unroll
  for (int nt = 0; nt < 8; ++nt) {
    int c = wave * 128 + nt * 16 + l16;
    float bias = bc[c];
    float v = 0.f;  // relu floor
    #pragma unroll
    for (int mt = 0; mt < 4; ++mt)
      #pragma unroll
      for (int r = 0; r < 4; ++r)
        v = fmaxf(v, acc[mt][nt][r] + bias);
    v = fmaxf(v, __shfl_xor(v, 16));
    v = fmaxf(v, __shfl_xor(v, 32));
    if (quad == 0)
      e[((size_t)z * B_SZ + b) * C_SZ + c] = v;
  }
}

// ---- kernel 2: feat[b][k] = k<512 ? e1-e2 : e1*e2  (bf16)
__global__ __launch_bounds__(256)
void feat_kernel(const float* __restrict__ e, unsigned short* __restrict__ featb) {
  int id = blockIdx.x * 256 + threadIdx.x;
  if (id >= B_SZ * 2 * C_SZ) return;
  int b = id >> 10, k = id & 1023, c = k & 511;
  float a = e[(size_t)b * C_SZ + c];
  float bb = e[(size_t)B_SZ * C_SZ + (size_t)b * C_SZ + c];
  float v = (k < C_SZ) ? (a - bb) : (a * bb);
  featb[id] = f2bf(v);
}

// ---- kernel 3: fc1+fc2 fused. pre = feat @ W1^T + b1; t = tanh(pre);
// partial[slice][b] = sum over this slice's 32 j-cols of t * W2[j].
// M=2048 batch, N=2048 hidden, K=1024. 64 slices (16 y-blocks x 4 waves).
__global__ __launch_bounds__(256, 4)
void fc1_kernel(const unsigned short* __restrict__ featb,
                const unsigned short* __restrict__ W1b,
                const float* __restrict__ b1, const float* __restrict__ W2,
                float* __restrict__ partial) {
  const int mbase = blockIdx.x * 32;
  const int tid = threadIdx.x;
  const int wave = tid >> 6, lane = tid & 63;
  const int l16 = lane & 15, quad = lane >> 4;
  const int nbase = blockIdx.y * 128 + wave * 32;
  const int koff = quad * 8;

  f32x4 acc[2][2];
  #pragma unroll
  for (int mt = 0; mt < 2; ++mt)
    #pragma unroll
    for (int nt = 0; nt < 2; ++nt)
      #pragma unroll
      for (int r = 0; r < 4; ++r) acc[mt][nt][r] = 0.f;

  #pragma unroll 4
  for (int ks = 0; ks < 32; ++ks) {
    bf16x8 a[2], bw[2];
    #pragma unroll
    for (int mt = 0; mt < 2; ++mt)
      a[mt] = *reinterpret_cast<const bf16x8*>(featb + (size_t)(mbase + mt * 16 + l16) * 1024 + ks * 32 + koff);
    #pragma unroll
    for (int nt = 0; nt < 2; ++nt)
      bw[nt] = *reinterpret_cast<const bf16x8*>(W1b + (size_t)(nbase + nt * 16 + l16) * 1024 + ks * 32 + koff);
    #pragma unroll
    for (int mt = 0; mt < 2; ++mt)
      #pragma unroll
      for (int nt = 0; nt < 2; ++nt)
        acc[mt][nt] = __builtin_amdgcn_mfma_f32_16x16x32_bf16(a[mt], bw[nt], acc[mt][nt], 0, 0, 0);
  }

  // epilogue: tanh in fp32, dot with W2, reduce over the 32 j-cols this wave owns
  float c[2][4];
  #pragma unroll
  for (int mt = 0; mt < 2; ++mt)
    #pragma unroll
    for (int r = 0; r < 4; ++r) c[mt][r] = 0.f;

  #pragma unroll
  for (int nt = 0; nt < 2; ++nt) {
    int j = nbase + nt * 16 + l16;
    float bias = b1[j];
    float w2 = W2[j];
    #pragma unroll
    for (int mt = 0; mt < 2; ++mt)
      #pragma unroll
      for (int r = 0; r < 4; ++r) {
        float pre = acc[mt][nt][r] + bias;
        pre = fminf(fmaxf(pre, -15.f), 15.f);
        float ex = __expf(2.f * pre);
        c[mt][r] += w2 * ((ex - 1.f) / (ex + 1.f));
      }
  }
  // butterfly-sum across the 16 lanes of each quad (j varies with l16, rows don't)
  #pragma unroll
  for (int off = 1; off <= 8; off <<= 1)
    #pragma unroll
    for (int mt = 0; mt < 2; ++mt)
      #pragma unroll
      for (int r = 0; r < 4; ++r)
        c[mt][r] += __shfl_xor(c[mt][r], off);

  if (l16 == 0) {
    int slice = blockIdx.y * 4 + wave;
    #pragma unroll
    for (int mt = 0; mt < 2; ++mt)
      #pragma unroll
      for (int r = 0; r < 4; ++r) {
        int brow = mbase + mt * 16 + quad * 4 + r;
        partial[(size_t)slice * B_SZ + brow] = c[mt][r];
      }
  }
}

// ---- kernel 4: out[b] = b2 + sum over 64 slices of partial[s][b]  (fp32 out!)
__global__ __launch_bounds__(256)
void finalize_kernel(const float* __restrict__ partial, const float* __restrict__ b2,
                     float* __restrict__ out) {
  int b = blockIdx.x * 256 + threadIdx.x;
  float s = b2[0];
  #pragma unroll 8
  for (int i = 0; i < 64; ++i) s += partial[(size_t)i * B_SZ + b];
  out[b] = s;
}

extern "C" void kernel_launch(void* const* d_in, const int* in_sizes, int n_in,
                              void* d_out, int out_size, void* d_ws, size_t ws_size,
                              hipStream_t stream) {
  const float* x1 = (const float*)d_in[0];
  const float* x2 = (const float*)d_in[1];
  const float* Wc = (const float*)d_in[2];
  const float* bc = (const float*)d_in[3];
  const float* W1 = (const float*)d_in[4];
  const float* b1 = (const float*)d_in[5];
  const float* W2 = (const float*)d_in[6];
  const float* b2 = (const float*)d_in[7];

  char* ws = (char*)d_ws;
  unsigned short* Wcb     = (unsigned short*)(ws);             // 327,680 B
  unsigned short* W1b     = (unsigned short*)(ws + 327680);    // 4,194,304 B
  float*          e       = (float*)(ws + 4521984);            // 8,388,608 B
  unsigned short* featb   = (unsigned short*)(ws + 12910592);  // 4,194,304 B
  float*          partial = (float*)(ws + 17104896);           // 524,288 B
  // total: 17,629,184 B

  convert_kernel<<<(C_SZ * KPAD + H_SZ * 2 * C_SZ + 255) / 256, 256, 0, stream>>>(Wc, W1, Wcb, W1b);
  encode_kernel<<<dim3(B_SZ, 2), 256, 0, stream>>>(x1, x2, Wcb, bc, e);
  feat_kernel<<<(B_SZ * 2 * C_SZ + 255) / 256, 256, 0, stream>>>(e, featb);
  fc1_kernel<<<dim3(B_SZ / 32, H_SZ / 128), 256, 0, stream>>>(featb, W1b, b1, W2, partial);
  finalize_kernel<<<B_SZ / 256, 256, 0, stream>>>(partial, b2, (float*)d_out);
}

// Round 4
// 489.328 us; speedup vs baseline: 1.1839x; 1.1839x over previous
//
#include <hip/hip_runtime.h>

// Model: e = maxpool_L(relu(x @ Wc^T + bc)); feat = [e1-e2, e1*e2];
//        h = tanh(feat @ W1^T + b1); out = h @ W2^T + b2   (all fp32 I/O)
// Sizes: B=2048, L=64, D=300, C=512, H=2048, O=1.
// R3 lesson: strided per-lane global loads (640B/2048B lane stride) shatter
// into ~64 transactions per wave load -> latency-bound (MfmaUtil 11%).
// R4: operands pre-swizzled to fragment-sequential layout
//   [tile16][kchunk][lane16][8elem]  -> every MFMA operand load is one
// contiguous 1KB wave transaction. fc2 stays fused in fc1 epilogue (fp32).

#define B_SZ 2048
#define L_SZ 64
#define D_SZ 300
#define C_SZ 512
#define H_SZ 2048
#define KPAD 320      // D padded to 32
#define NKC 40        // KPAD/8 kchunks for encode
#define LDSPITCH 328  // x-tile LDS pitch (bank-conflict ~1%/block, fine)

typedef __bf16 bf16x8 __attribute__((ext_vector_type(8)));
typedef float f32x4 __attribute__((ext_vector_type(4)));

__device__ __forceinline__ unsigned short f2bf(float f) {
  unsigned int u = __float_as_uint(f);
  u += 0x7fffu + ((u >> 16) & 1u);   // RNE
  return (unsigned short)(u >> 16);
}

// ---- kernel 0: build swizzled bf16 weights.
// WcSwz[(c/16)*40 + kc][l16=c%16][8]  (zero-pad k>=300)
// W1Swz[(j/16)*128 + kc][l16=j%16][8]
__global__ __launch_bounds__(256)
void convert_kernel(const float* __restrict__ Wc, const float* __restrict__ W1,
                    unsigned short* __restrict__ WcSwz, unsigned short* __restrict__ W1Swz) {
  int id = blockIdx.x * 256 + threadIdx.x;
  if (id < C_SZ * NKC) {                      // 20480 threads: (c, kc)
    int c = id / NKC, kc = id - c * NKC;
    unsigned short tmp[8];
    #pragma unroll
    for (int i = 0; i < 8; ++i) {
      int k = kc * 8 + i;
      tmp[i] = (k < D_SZ) ? f2bf(Wc[c * D_SZ + k]) : (unsigned short)0;
    }
    unsigned short* dst = WcSwz + (((c >> 4) * NKC + kc) * 16 + (c & 15)) * 8;
    *reinterpret_cast<uint4*>(dst) = *reinterpret_cast<uint4*>(tmp);
    return;
  }
  id -= C_SZ * NKC;
  if (id < H_SZ * 128) {                      // 262144 threads: (j, kc)
    int j = id >> 7, kc = id & 127;
    const float* src = W1 + (size_t)j * 1024 + kc * 8;
    unsigned short tmp[8];
    #pragma unroll
    for (int i = 0; i < 8; ++i) tmp[i] = f2bf(src[i]);
    unsigned short* dst = W1Swz + (((j >> 4) * 128 + kc) * 16 + (j & 15)) * 8;
    *reinterpret_cast<uint4*>(dst) = *reinterpret_cast<uint4*>(tmp);
  }
}

// ---- kernel 1: encode. One block per (batch, which-input). M=64, N=512, K=320.
__global__ __launch_bounds__(256)
void encode_kernel(const float* __restrict__ x1, const float* __restrict__ x2,
                   const unsigned short* __restrict__ WcSwz,
                   const float* __restrict__ bc, float* __restrict__ e) {
  const int b = blockIdx.x, z = blockIdx.y;
  const float* __restrict__ x = (z ? x2 : x1) + (size_t)b * (L_SZ * D_SZ);
  __shared__ unsigned short xs[L_SZ * LDSPITCH];  // 41,984 B -> 3 blocks/CU
  const int tid = threadIdx.x;

  // stage x[b] fp32 -> bf16 LDS (75 float4 per word-row)
  const float4* __restrict__ xv = reinterpret_cast<const float4*>(x);
  for (int i = tid; i < (L_SZ * D_SZ / 4); i += 256) {
    float4 v = xv[i];
    int word = i / 75, col = (i - word * 75) * 4;
    unsigned int lo = (unsigned int)f2bf(v.x) | ((unsigned int)f2bf(v.y) << 16);
    unsigned int hi = (unsigned int)f2bf(v.z) | ((unsigned int)f2bf(v.w) << 16);
    *reinterpret_cast<uint2*>(&xs[word * LDSPITCH + col]) = make_uint2(lo, hi);
  }
  for (int i = tid; i < L_SZ * (KPAD - D_SZ); i += 256) {  // zero K-pad cols
    int word = i / 20, c = D_SZ + (i - word * 20);
    xs[word * LDSPITCH + c] = 0;
  }
  __syncthreads();

  const int wave = tid >> 6, lane = tid & 63;
  const int l16 = lane & 15, quad = lane >> 4;
  const int koff = quad * 8;

  f32x4 acc[4][8];
  #pragma unroll
  for (int mt = 0; mt < 4; ++mt)
    #pragma unroll
    for (int nt = 0; nt < 8; ++nt)
      #pragma unroll
      for (int r = 0; r < 4; ++r) acc[mt][nt][r] = 0.f;

  // wave w covers channels [w*128, w*128+128); B-loads are 1KB wave-contiguous
  #pragma unroll
  for (int ks = 0; ks < KPAD / 32; ++ks) {
    bf16x8 a[4];
    #pragma unroll
    for (int mt = 0; mt < 4; ++mt)
      a[mt] = *reinterpret_cast<const bf16x8*>(&xs[(mt * 16 + l16) * LDSPITCH + ks * 32 + koff]);
    #pragma unroll
    for (int nt = 0; nt < 8; ++nt) {
      const unsigned short* bp =
          WcSwz + ((((wave * 8 + nt) * NKC) + ks * 4 + quad) * 16 + l16) * 8;
      bf16x8 bw = *reinterpret_cast<const bf16x8*>(bp);
      #pragma unroll
      for (int mt = 0; mt < 4; ++mt)
        acc[mt][nt] = __builtin_amdgcn_mfma_f32_16x16x32_bf16(a[mt], bw, acc[mt][nt], 0, 0, 0);
    }
  }

  // +bias, relu, max over the 64 words (C/D: row=quad*4+r, col=l16)
  #pragma unroll
  for (int nt = 0; nt < 8; ++nt) {
    int c = wave * 128 + nt * 16 + l16;
    float bias = bc[c];
    float v = 0.f;  // relu floor
    #pragma unroll
    for (int mt = 0; mt < 4; ++mt)
      #pragma unroll
      for (int r = 0; r < 4; ++r)
        v = fmaxf(v, acc[mt][nt][r] + bias);
    v = fmaxf(v, __shfl_xor(v, 16));
    v = fmaxf(v, __shfl_xor(v, 32));
    if (quad == 0)
      e[((size_t)z * B_SZ + b) * C_SZ + c] = v;
  }
}

// ---- kernel 2: featSwz[(b/16)*128 + kc][b%16][8], feat[k<512]=e1-e2 else e1*e2
__global__ __launch_bounds__(256)
void feat_kernel(const float* __restrict__ e, unsigned short* __restrict__ featSwz) {
  int id = blockIdx.x * 256 + threadIdx.x;   // (b, kc), kc in [0,128)
  if (id >= B_SZ * 128) return;
  int b = id >> 7, kc = id & 127;
  unsigned short tmp[8];
  #pragma unroll
  for (int i = 0; i < 8; ++i) {
    int k = kc * 8 + i, c = k & 511;
    float a = e[(size_t)b * C_SZ + c];
    float bb = e[(size_t)B_SZ * C_SZ + (size_t)b * C_SZ + c];
    tmp[i] = f2bf((k < C_SZ) ? (a - bb) : (a * bb));
  }
  unsigned short* dst = featSwz + (((b >> 4) * 128 + kc) * 16 + (b & 15)) * 8;
  *reinterpret_cast<uint4*>(dst) = *reinterpret_cast<uint4*>(tmp);
}

// ---- kernel 3: fc1+fc2 fused. pre = feat @ W1^T + b1; t = tanh(pre);
// partial[slice][b] = sum over this wave's 32 j-cols of t * W2[j].
__global__ __launch_bounds__(256, 4)
void fc1_kernel(const unsigned short* __restrict__ featSwz,
                const unsigned short* __restrict__ W1Swz,
                const float* __restrict__ b1, const float* __restrict__ W2,
                float* __restrict__ partial) {
  const int mbase = blockIdx.x * 32;
  const int tid = threadIdx.x;
  const int wave = tid >> 6, lane = tid & 63;
  const int l16 = lane & 15, quad = lane >> 4;
  const int nbase = blockIdx.y * 128 + wave * 32;

  f32x4 acc[2][2];
  #pragma unroll
  for (int mt = 0; mt < 2; ++mt)
    #pragma unroll
    for (int nt = 0; nt < 2; ++nt)
      #pragma unroll
      for (int r = 0; r < 4; ++r) acc[mt][nt][r] = 0.f;

  #pragma unroll 4
  for (int ks = 0; ks < 32; ++ks) {
    bf16x8 a[2], bw[2];
    #pragma unroll
    for (int mt = 0; mt < 2; ++mt)
      a[mt] = *reinterpret_cast<const bf16x8*>(
          featSwz + (((size_t)(blockIdx.x * 2 + mt) * 128 + ks * 4 + quad) * 16 + l16) * 8);
    #pragma unroll
    for (int nt = 0; nt < 2; ++nt)
      bw[nt] = *reinterpret_cast<const bf16x8*>(
          W1Swz + (((size_t)(blockIdx.y * 8 + wave * 2 + nt) * 128 + ks * 4 + quad) * 16 + l16) * 8);
    #pragma unroll
    for (int mt = 0; mt < 2; ++mt)
      #pragma unroll
      for (int nt = 0; nt < 2; ++nt)
        acc[mt][nt] = __builtin_amdgcn_mfma_f32_16x16x32_bf16(a[mt], bw[nt], acc[mt][nt], 0, 0, 0);
  }

  // epilogue: tanh in fp32, dot with W2, reduce over this wave's 32 j-cols
  float c[2][4];
  #pragma unroll
  for (int mt = 0; mt < 2; ++mt)
    #pragma unroll
    for (int r = 0; r < 4; ++r) c[mt][r] = 0.f;

  #pragma unroll
  for (int nt = 0; nt < 2; ++nt) {
    int j = nbase + nt * 16 + l16;
    float bias = b1[j];
    float w2 = W2[j];
    #pragma unroll
    for (int mt = 0; mt < 2; ++mt)
      #pragma unroll
      for (int r = 0; r < 4; ++r) {
        float pre = acc[mt][nt][r] + bias;
        pre = fminf(fmaxf(pre, -15.f), 15.f);
        float ex = __expf(2.f * pre);
        c[mt][r] += w2 * ((ex - 1.f) / (ex + 1.f));
      }
  }
  #pragma unroll
  for (int off = 1; off <= 8; off <<= 1)
    #pragma unroll
    for (int mt = 0; mt < 2; ++mt)
      #pragma unroll
      for (int r = 0; r < 4; ++r)
        c[mt][r] += __shfl_xor(c[mt][r], off);

  if (l16 == 0) {
    int slice = blockIdx.y * 4 + wave;
    #pragma unroll
    for (int mt = 0; mt < 2; ++mt)
      #pragma unroll
      for (int r = 0; r < 4; ++r) {
        int brow = mbase + mt * 16 + quad * 4 + r;
        partial[(size_t)slice * B_SZ + brow] = c[mt][r];
      }
  }
}

// ---- kernel 4: out[b] = b2 + sum over 64 slices of partial[s][b]  (fp32 out)
__global__ __launch_bounds__(256)
void finalize_kernel(const float* __restrict__ partial, const float* __restrict__ b2,
                     float* __restrict__ out) {
  int b = blockIdx.x * 256 + threadIdx.x;
  float s = b2[0];
  #pragma unroll 8
  for (int i = 0; i < 64; ++i) s += partial[(size_t)i * B_SZ + b];
  out[b] = s;
}

extern "C" void kernel_launch(void* const* d_in, const int* in_sizes, int n_in,
                              void* d_out, int out_size, void* d_ws, size_t ws_size,
                              hipStream_t stream) {
  const float* x1 = (const float*)d_in[0];
  const float* x2 = (const float*)d_in[1];
  const float* Wc = (const float*)d_in[2];
  const float* bc = (const float*)d_in[3];
  const float* W1 = (const float*)d_in[4];
  const float* b1 = (const float*)d_in[5];
  const float* W2 = (const float*)d_in[6];
  const float* b2 = (const float*)d_in[7];

  char* ws = (char*)d_ws;
  unsigned short* WcSwz   = (unsigned short*)(ws);             // 327,680 B
  unsigned short* W1Swz   = (unsigned short*)(ws + 327680);    // 4,194,304 B
  float*          e       = (float*)(ws + 4521984);            // 8,388,608 B
  unsigned short* featSwz = (unsigned short*)(ws + 12910592);  // 4,194,304 B
  float*          partial = (float*)(ws + 17104896);           // 524,288 B
  // total: 17,629,184 B

  {
    int total = C_SZ * NKC + H_SZ * 128;  // 282,624
    convert_kernel<<<(total + 255) / 256, 256, 0, stream>>>(Wc, W1, WcSwz, W1Swz);
  }
  encode_kernel<<<dim3(B_SZ, 2), 256, 0, stream>>>(x1, x2, WcSwz, bc, e);
  feat_kernel<<<(B_SZ * 128 + 255) / 256, 256, 0, stream>>>(e, featSwz);
  fc1_kernel<<<dim3(B_SZ / 32, H_SZ / 128), 256, 0, stream>>>(featSwz, W1Swz, b1, W2, partial);
  finalize_kernel<<<B_SZ / 256, 256, 0, stream>>>(partial, b2, (float*)d_out);
}